// Round 1
// baseline (1452.046 us; speedup 1.0000x reference)
//
#include <hip/hip_runtime.h>
#include <math.h>

#define B_   32
#define C_   256
#define N_   4096
#define N8_  512
#define C8_  32
#define EPS_ 1e-5f

// ---------------- kernel 1a: pooled[b,c] = max_n x[b,c,n] ----------------
__global__ __launch_bounds__(256) void k_pool(const float* __restrict__ x,
                                              float* __restrict__ pooled) {
  int b = blockIdx.y, cg = blockIdx.x;   // cg: 16 channel-groups of 16
  int t = threadIdx.x;
  int cl = t >> 4;   // channel within group
  int w  = t & 15;   // worker within channel
  int c = cg * 16 + cl;
  const float* xp = x + ((size_t)b * C_ + c) * N_;
  float4 vm = make_float4(-3.402823466e+38f, -3.402823466e+38f,
                          -3.402823466e+38f, -3.402823466e+38f);
  for (int chunk = 0; chunk < N_ / 64; ++chunk) {
    float4 v = *(const float4*)(xp + chunk * 64 + w * 4);
    vm.x = fmaxf(vm.x, v.x); vm.y = fmaxf(vm.y, v.y);
    vm.z = fmaxf(vm.z, v.z); vm.w = fmaxf(vm.w, v.w);
  }
  float m = fmaxf(fmaxf(vm.x, vm.y), fmaxf(vm.z, vm.w));
  __shared__ float part[16][16];
  part[cl][w] = m;
  __syncthreads();
  if (t < 16) {
    float mm = part[t][0];
    #pragma unroll
    for (int i = 1; i < 16; ++i) mm = fmaxf(mm, part[t][i]);
    pooled[b * C_ + cg * 16 + t] = mm;
  }
}

// ---------------- kernel 1b: s = sigmoid(relu(pooled@W1^T)@W2^T) ----------
__global__ __launch_bounds__(256) void k_semlp(const float* __restrict__ pooled,
                                               const float* __restrict__ W1,
                                               const float* __restrict__ W2,
                                               float* __restrict__ s) {
  int b = blockIdx.x, t = threadIdx.x;
  __shared__ float p[C_];
  __shared__ float h[C8_];
  p[t] = pooled[b * C_ + t];
  __syncthreads();
  if (t < C8_) {
    float a = 0.f;
    for (int c = 0; c < C_; ++c) a = fmaf(p[c], W1[t * C_ + c], a);
    h[t] = fmaxf(a, 0.f);
  }
  __syncthreads();
  float a = 0.f;
  #pragma unroll
  for (int j = 0; j < C8_; ++j) a = fmaf(h[j], W2[t * C8_ + j], a);
  s[b * C_ + t] = 1.f / (1.f + __expf(-a));
}

// ---------------- kernel 2: q/k = relu(bn(W @ x^T)) ----------------------
// W rows 0..511 -> Wq/bn1 -> q ; rows 512..1023 -> Wk/bn2 -> k
// Both operands K-contiguous (NT GEMM). Tile 64x64, 4x4 per thread, K-chunk 16.
__global__ __launch_bounds__(256) void k_qk(const float* __restrict__ x,
    const float* __restrict__ Wq, const float* __restrict__ Wk,
    const float* __restrict__ g1, const float* __restrict__ b1,
    const float* __restrict__ m1, const float* __restrict__ v1,
    const float* __restrict__ g2, const float* __restrict__ b2,
    const float* __restrict__ m2, const float* __restrict__ v2,
    float* __restrict__ q, float* __restrict__ k) {
  int b  = blockIdx.z;
  int rb = blockIdx.y;  // 0..15 (row block of 64 in the 1024-row concat W)
  int cb = blockIdx.x;  // 0..3  (channel block of 64)
  bool isq = rb < 8;
  const float* W  = isq ? (Wq + (size_t)rb * 64 * N_)
                        : (Wk + (size_t)(rb - 8) * 64 * N_);
  const float* xb = x + (size_t)b * C_ * N_ + (size_t)cb * 64 * N_;
  __shared__ float As[16][64];
  __shared__ float Bs[16][64];
  int t = threadIdx.x;
  int lrow = t >> 2;          // 0..63
  int kq   = (t & 3) * 4;     // 0,4,8,12
  int tx = t & 15, ty = t >> 4;
  float acc[4][4] = {{0.f, 0.f, 0.f, 0.f}, {0.f, 0.f, 0.f, 0.f},
                     {0.f, 0.f, 0.f, 0.f}, {0.f, 0.f, 0.f, 0.f}};
  for (int kk = 0; kk < N_; kk += 16) {
    float4 av = *(const float4*)(W  + (size_t)lrow * N_ + kk + kq);
    float4 bv = *(const float4*)(xb + (size_t)lrow * N_ + kk + kq);
    As[kq + 0][lrow] = av.x; As[kq + 1][lrow] = av.y;
    As[kq + 2][lrow] = av.z; As[kq + 3][lrow] = av.w;
    Bs[kq + 0][lrow] = bv.x; Bs[kq + 1][lrow] = bv.y;
    Bs[kq + 2][lrow] = bv.z; Bs[kq + 3][lrow] = bv.w;
    __syncthreads();
    #pragma unroll
    for (int kt = 0; kt < 16; ++kt) {
      float4 a  = *(const float4*)&As[kt][ty * 4];
      float4 bb = *(const float4*)&Bs[kt][tx * 4];
      acc[0][0] = fmaf(a.x, bb.x, acc[0][0]);
      acc[0][1] = fmaf(a.x, bb.y, acc[0][1]);
      acc[0][2] = fmaf(a.x, bb.z, acc[0][2]);
      acc[0][3] = fmaf(a.x, bb.w, acc[0][3]);
      acc[1][0] = fmaf(a.y, bb.x, acc[1][0]);
      acc[1][1] = fmaf(a.y, bb.y, acc[1][1]);
      acc[1][2] = fmaf(a.y, bb.z, acc[1][2]);
      acc[1][3] = fmaf(a.y, bb.w, acc[1][3]);
      acc[2][0] = fmaf(a.z, bb.x, acc[2][0]);
      acc[2][1] = fmaf(a.z, bb.y, acc[2][1]);
      acc[2][2] = fmaf(a.z, bb.z, acc[2][2]);
      acc[2][3] = fmaf(a.z, bb.w, acc[2][3]);
      acc[3][0] = fmaf(a.w, bb.x, acc[3][0]);
      acc[3][1] = fmaf(a.w, bb.y, acc[3][1]);
      acc[3][2] = fmaf(a.w, bb.z, acc[3][2]);
      acc[3][3] = fmaf(a.w, bb.w, acc[3][3]);
    }
    __syncthreads();
  }
  const float* G  = isq ? g1 : g2;
  const float* Bb = isq ? b1 : b2;
  const float* M  = isq ? m1 : m2;
  const float* V  = isq ? v1 : v2;
  int lr0 = (isq ? rb : rb - 8) * 64 + ty * 4;
  float* dst = (isq ? q : k) + (size_t)b * N8_ * C_;
  #pragma unroll
  for (int i = 0; i < 4; ++i) {
    int lr = lr0 + i;
    float sc = G[lr] / sqrtf(V[lr] + EPS_);
    float bi = Bb[lr] - M[lr] * sc;
    float4 o;
    o.x = fmaxf(fmaf(acc[i][0], sc, bi), 0.f);
    o.y = fmaxf(fmaf(acc[i][1], sc, bi), 0.f);
    o.z = fmaxf(fmaf(acc[i][2], sc, bi), 0.f);
    o.w = fmaxf(fmaf(acc[i][3], sc, bi), 0.f);
    *(float4*)(dst + (size_t)lr * C_ + cb * 64 + tx * 4) = o;
  }
}

// -------- kernel 3: sim -> stable softmax(-sim) -> fold alpha*s -> aff2 ---
// Block handles (b, 16 rows c). Thread t owns column d=t.
__global__ __launch_bounds__(256) void k_simsoft(const float* __restrict__ q,
    const float* __restrict__ k, const float* __restrict__ s,
    const float* __restrict__ alpha, float* __restrict__ aff2) {
  int b = blockIdx.y, ct = blockIdx.x;  // ct: 0..15
  int t = threadIdx.x;
  __shared__ float kT[N8_][16];
  const float* kb = k + (size_t)b * N8_ * C_;
  int c0 = ct * 16;
  for (int chunk = 0; chunk < N8_ / 16; ++chunk) {
    int row = chunk * 16 + (t >> 4);
    kT[row][t & 15] = kb[(size_t)row * C_ + c0 + (t & 15)];
  }
  __syncthreads();
  float acc[16];
  #pragma unroll
  for (int i = 0; i < 16; ++i) acc[i] = 0.f;
  const float* qb = q + (size_t)b * N8_ * C_;
  for (int kk = 0; kk < N8_; ++kk) {
    float qv = qb[(size_t)kk * C_ + t];
    float4 k0 = *(const float4*)&kT[kk][0];
    float4 k1 = *(const float4*)&kT[kk][4];
    float4 k2 = *(const float4*)&kT[kk][8];
    float4 k3 = *(const float4*)&kT[kk][12];
    acc[0]  = fmaf(k0.x, qv, acc[0]);  acc[1]  = fmaf(k0.y, qv, acc[1]);
    acc[2]  = fmaf(k0.z, qv, acc[2]);  acc[3]  = fmaf(k0.w, qv, acc[3]);
    acc[4]  = fmaf(k1.x, qv, acc[4]);  acc[5]  = fmaf(k1.y, qv, acc[5]);
    acc[6]  = fmaf(k1.z, qv, acc[6]);  acc[7]  = fmaf(k1.w, qv, acc[7]);
    acc[8]  = fmaf(k2.x, qv, acc[8]);  acc[9]  = fmaf(k2.y, qv, acc[9]);
    acc[10] = fmaf(k2.z, qv, acc[10]); acc[11] = fmaf(k2.w, qv, acc[11]);
    acc[12] = fmaf(k3.x, qv, acc[12]); acc[13] = fmaf(k3.y, qv, acc[13]);
    acc[14] = fmaf(k3.z, qv, acc[14]); acc[15] = fmaf(k3.w, qv, acc[15]);
  }
  int lane = t & 63, wid = t >> 6;
  __shared__ float wmin[16][4];
  __shared__ float wsum[16][4];
  #pragma unroll
  for (int i = 0; i < 16; ++i) {
    float v = acc[i];
    for (int off = 32; off > 0; off >>= 1) v = fminf(v, __shfl_xor(v, off, 64));
    if (lane == 0) wmin[i][wid] = v;
  }
  __syncthreads();
  float w[16];
  #pragma unroll
  for (int i = 0; i < 16; ++i) {
    float m = fminf(fminf(wmin[i][0], wmin[i][1]), fminf(wmin[i][2], wmin[i][3]));
    w[i] = __expf(m - acc[i]);   // arg <= 0: no overflow; row-min term == 1
  }
  #pragma unroll
  for (int i = 0; i < 16; ++i) {
    float v = w[i];
    for (int off = 32; off > 0; off >>= 1) v += __shfl_xor(v, off, 64);
    if (lane == 0) wsum[i][wid] = v;
  }
  __syncthreads();
  float fac = alpha[0] * s[b * C_ + t];
  float* ab = aff2 + (size_t)b * C_ * C_;
  #pragma unroll
  for (int i = 0; i < 16; ++i) {
    float Z = wsum[i][0] + wsum[i][1] + wsum[i][2] + wsum[i][3];
    ab[(size_t)(c0 + i) * C_ + t] = fac * w[i] / Z;
  }
}

// ---------------- kernel 4: out = aff2 @ x + x  (per batch) ---------------
__global__ __launch_bounds__(256) void k_out(const float* __restrict__ aff2,
    const float* __restrict__ x, float* __restrict__ out) {
  int b   = blockIdx.z;
  int cbl = blockIdx.y;  // 0..3
  int nb  = blockIdx.x;  // 0..63
  int t = threadIdx.x;
  __shared__ float As[16][64];
  __shared__ float Bs[16][64];
  const float* ab = aff2 + (size_t)b * C_ * C_ + (size_t)cbl * 64 * C_;
  const float* xb = x + (size_t)b * C_ * N_;
  int n0 = nb * 64;
  int arow = t >> 2, akq = (t & 3) * 4;
  int brow = t >> 4, bnq = (t & 15) * 4;
  int tx = t & 15, ty = t >> 4;
  float acc[4][4] = {{0.f, 0.f, 0.f, 0.f}, {0.f, 0.f, 0.f, 0.f},
                     {0.f, 0.f, 0.f, 0.f}, {0.f, 0.f, 0.f, 0.f}};
  for (int kk = 0; kk < C_; kk += 16) {
    float4 av = *(const float4*)(ab + (size_t)arow * C_ + kk + akq);
    As[akq + 0][arow] = av.x; As[akq + 1][arow] = av.y;
    As[akq + 2][arow] = av.z; As[akq + 3][arow] = av.w;
    float4 bv = *(const float4*)(xb + (size_t)(kk + brow) * N_ + n0 + bnq);
    *(float4*)&Bs[brow][bnq] = bv;
    __syncthreads();
    #pragma unroll
    for (int kt = 0; kt < 16; ++kt) {
      float4 a  = *(const float4*)&As[kt][ty * 4];
      float4 bb = *(const float4*)&Bs[kt][tx * 4];
      acc[0][0] = fmaf(a.x, bb.x, acc[0][0]);
      acc[0][1] = fmaf(a.x, bb.y, acc[0][1]);
      acc[0][2] = fmaf(a.x, bb.z, acc[0][2]);
      acc[0][3] = fmaf(a.x, bb.w, acc[0][3]);
      acc[1][0] = fmaf(a.y, bb.x, acc[1][0]);
      acc[1][1] = fmaf(a.y, bb.y, acc[1][1]);
      acc[1][2] = fmaf(a.y, bb.z, acc[1][2]);
      acc[1][3] = fmaf(a.y, bb.w, acc[1][3]);
      acc[2][0] = fmaf(a.z, bb.x, acc[2][0]);
      acc[2][1] = fmaf(a.z, bb.y, acc[2][1]);
      acc[2][2] = fmaf(a.z, bb.z, acc[2][2]);
      acc[2][3] = fmaf(a.z, bb.w, acc[2][3]);
      acc[3][0] = fmaf(a.w, bb.x, acc[3][0]);
      acc[3][1] = fmaf(a.w, bb.y, acc[3][1]);
      acc[3][2] = fmaf(a.w, bb.z, acc[3][2]);
      acc[3][3] = fmaf(a.w, bb.w, acc[3][3]);
    }
    __syncthreads();
  }
  #pragma unroll
  for (int i = 0; i < 4; ++i) {
    int c = cbl * 64 + ty * 4 + i;
    float4 xr = *(const float4*)(xb + (size_t)c * N_ + n0 + tx * 4);
    float4 o;
    o.x = acc[i][0] + xr.x;
    o.y = acc[i][1] + xr.y;
    o.z = acc[i][2] + xr.z;
    o.w = acc[i][3] + xr.w;
    *(float4*)(out + ((size_t)b * C_ + c) * N_ + n0 + tx * 4) = o;
  }
}

extern "C" void kernel_launch(void* const* d_in, const int* in_sizes, int n_in,
                              void* d_out, int out_size, void* d_ws, size_t ws_size,
                              hipStream_t stream) {
  const float* x     = (const float*)d_in[0];
  const float* Wq    = (const float*)d_in[1];
  const float* g1    = (const float*)d_in[2];
  const float* b1    = (const float*)d_in[3];
  const float* m1    = (const float*)d_in[4];
  const float* v1    = (const float*)d_in[5];
  const float* Wk    = (const float*)d_in[6];
  const float* g2    = (const float*)d_in[7];
  const float* b2    = (const float*)d_in[8];
  const float* m2    = (const float*)d_in[9];
  const float* v2    = (const float*)d_in[10];
  const float* W1    = (const float*)d_in[11];
  const float* W2    = (const float*)d_in[12];
  const float* alpha = (const float*)d_in[13];
  float* out = (float*)d_out;

  float* ws     = (float*)d_ws;
  float* q      = ws;                                 // 32*512*256
  float* kbuf   = q + (size_t)B_ * N8_ * C_;          // 32*512*256
  float* aff2   = kbuf + (size_t)B_ * N8_ * C_;       // 32*256*256
  float* pooled = aff2 + (size_t)B_ * C_ * C_;        // 32*256
  float* s      = pooled + B_ * C_;                   // 32*256

  k_pool<<<dim3(16, B_), 256, 0, stream>>>(x, pooled);
  k_semlp<<<dim3(B_), 256, 0, stream>>>(pooled, W1, W2, s);
  k_qk<<<dim3(4, 16, B_), 256, 0, stream>>>(x, Wq, Wk, g1, b1, m1, v1,
                                            g2, b2, m2, v2, q, kbuf);
  k_simsoft<<<dim3(16, B_), 256, 0, stream>>>(q, kbuf, s, alpha, aff2);
  k_out<<<dim3(64, 4, B_), 256, 0, stream>>>(aff2, x, out);
}

// Round 2
// 816.522 us; speedup vs baseline: 1.7783x; 1.7783x over previous
//
#include <hip/hip_runtime.h>
#include <math.h>

#define B_   32
#define C_   256
#define N_   4096
#define N8_  512
#define C8_  32
#define EPS_ 1e-5f

typedef __attribute__((ext_vector_type(8))) short short8;
typedef __attribute__((ext_vector_type(4))) float f32x4;

__device__ __forceinline__ ushort f2bf(float v) {
  unsigned u = __float_as_uint(v);
  unsigned r = (u + 0x7fffu + ((u >> 16) & 1u)) >> 16;  // RNE to bf16
  return (ushort)r;
}
__device__ __forceinline__ float bf2f(ushort h) {
  return __uint_as_float(((unsigned)h) << 16);
}

// ------------- fp32 -> (bf16 hi, bf16 lo) split conversion ----------------
__global__ __launch_bounds__(256) void k_cvt(const float* __restrict__ src,
                                             ushort* __restrict__ hi,
                                             ushort* __restrict__ lo, int n4) {
  int i = blockIdx.x * 256 + threadIdx.x;
  int stride = gridDim.x * 256;
  for (; i < n4; i += stride) {
    float4 v = ((const float4*)src)[i];
    ushort4 h, l;
    h.x = f2bf(v.x); l.x = f2bf(v.x - bf2f(h.x));
    h.y = f2bf(v.y); l.y = f2bf(v.y - bf2f(h.y));
    h.z = f2bf(v.z); l.z = f2bf(v.z - bf2f(h.z));
    h.w = f2bf(v.w); l.w = f2bf(v.w - bf2f(h.w));
    ((ushort4*)hi)[i] = h;
    ((ushort4*)lo)[i] = l;
  }
}

// ---------------- kernel 1a: pooled[b,c] = max_n x[b,c,n] ----------------
__global__ __launch_bounds__(256) void k_pool(const float* __restrict__ x,
                                              float* __restrict__ pooled) {
  int b = blockIdx.y, cg = blockIdx.x;
  int t = threadIdx.x;
  int cl = t >> 4, w = t & 15;
  int c = cg * 16 + cl;
  const float* xp = x + ((size_t)b * C_ + c) * N_;
  float4 vm = make_float4(-3.402823466e+38f, -3.402823466e+38f,
                          -3.402823466e+38f, -3.402823466e+38f);
  for (int chunk = 0; chunk < N_ / 64; ++chunk) {
    float4 v = *(const float4*)(xp + chunk * 64 + w * 4);
    vm.x = fmaxf(vm.x, v.x); vm.y = fmaxf(vm.y, v.y);
    vm.z = fmaxf(vm.z, v.z); vm.w = fmaxf(vm.w, v.w);
  }
  float m = fmaxf(fmaxf(vm.x, vm.y), fmaxf(vm.z, vm.w));
  __shared__ float part[16][16];
  part[cl][w] = m;
  __syncthreads();
  if (t < 16) {
    float mm = part[t][0];
    #pragma unroll
    for (int i = 1; i < 16; ++i) mm = fmaxf(mm, part[t][i]);
    pooled[b * C_ + cg * 16 + t] = mm;
  }
}

// ---------------- kernel 1b: s = sigmoid(relu(pooled@W1^T)@W2^T) ----------
__global__ __launch_bounds__(256) void k_semlp(const float* __restrict__ pooled,
                                               const float* __restrict__ W1,
                                               const float* __restrict__ W2,
                                               float* __restrict__ s) {
  int b = blockIdx.x, t = threadIdx.x;
  __shared__ float p[C_];
  __shared__ float h[C8_];
  p[t] = pooled[b * C_ + t];
  __syncthreads();
  if (t < C8_) {
    float a = 0.f;
    for (int c = 0; c < C_; ++c) a = fmaf(p[c], W1[t * C_ + c], a);
    h[t] = fmaxf(a, 0.f);
  }
  __syncthreads();
  float a = 0.f;
  #pragma unroll
  for (int j = 0; j < C8_; ++j) a = fmaf(h[j], W2[t * C8_ + j], a);
  s[b * C_ + t] = 1.f / (1.f + __expf(-a));
}

// ------- kernel 2 (MFMA): q/k = relu(bn(W @ x^T)), split-bf16 hi/lo -------
// W concat [1024][4096] bf16 (hi,lo); X [32][256][4096] bf16 (hi,lo).
// 128x128 tile, BK=32, 2x2 waves x 4x4 frags of 16x16x32, global_load_lds w16.
__global__ __launch_bounds__(256) void k_qk_mfma(
    const ushort* __restrict__ Wh, const ushort* __restrict__ Wl,
    const ushort* __restrict__ Xh, const ushort* __restrict__ Xl,
    const float* __restrict__ g1, const float* __restrict__ b1,
    const float* __restrict__ m1, const float* __restrict__ v1,
    const float* __restrict__ g2, const float* __restrict__ b2,
    const float* __restrict__ m2, const float* __restrict__ v2,
    float* __restrict__ q, float* __restrict__ k) {
  int b  = blockIdx.z;
  int rb = blockIdx.y;  // 0..7 : rows rb*128.. of the 1024-row concat W
  int cb = blockIdx.x;  // 0..1 : channel block of 128
  __shared__ ushort Ah[128 * 32];
  __shared__ ushort Al[128 * 32];
  __shared__ ushort Bh[128 * 32];
  __shared__ ushort Bl[128 * 32];
  int t = threadIdx.x, wave = t >> 6, lane = t & 63;
  int wr = (wave >> 1) * 64, wc = (wave & 1) * 64;

  // staging: per instruction a wave covers 16 rows (4 lanes/row, 16B each)
  int srow = wave * 16 + (lane >> 2);
  int skof = (lane & 3) * 8;
  size_t aoff = (size_t)(rb * 128 + srow) * N_ + skof;
  size_t boff = ((size_t)b * C_ + cb * 128 + srow) * N_ + skof;
  int lb0 = (wave * 16) * 32;  // wave-uniform LDS base (ushort idx)

  f32x4 acc[4][4];
  #pragma unroll
  for (int mi = 0; mi < 4; ++mi)
    #pragma unroll
    for (int ni = 0; ni < 4; ++ni)
      acc[mi][ni] = (f32x4){0.f, 0.f, 0.f, 0.f};

  int fr = lane & 15, quad = lane >> 4;
  for (int k0 = 0; k0 < N_; k0 += 32) {
    #pragma unroll
    for (int seg = 0; seg < 2; ++seg) {
      size_t ga = aoff + (size_t)seg * 64 * N_ + k0;
      size_t gb = boff + (size_t)seg * 64 * N_ + k0;
      int lb = lb0 + seg * 64 * 32;
      __builtin_amdgcn_global_load_lds(
          (const __attribute__((address_space(1))) void*)(Wh + ga),
          (__attribute__((address_space(3))) void*)(&Ah[lb]), 16, 0, 0);
      __builtin_amdgcn_global_load_lds(
          (const __attribute__((address_space(1))) void*)(Wl + ga),
          (__attribute__((address_space(3))) void*)(&Al[lb]), 16, 0, 0);
      __builtin_amdgcn_global_load_lds(
          (const __attribute__((address_space(1))) void*)(Xh + gb),
          (__attribute__((address_space(3))) void*)(&Bh[lb]), 16, 0, 0);
      __builtin_amdgcn_global_load_lds(
          (const __attribute__((address_space(1))) void*)(Xl + gb),
          (__attribute__((address_space(3))) void*)(&Bl[lb]), 16, 0, 0);
    }
    __syncthreads();
    short8 af[4][2], bf[4][2];
    #pragma unroll
    for (int i = 0; i < 4; ++i) {
      int ra = (wr + i * 16 + fr) * 32 + quad * 8;
      af[i][0] = *(const short8*)&Ah[ra];
      af[i][1] = *(const short8*)&Al[ra];
      int rbx = (wc + i * 16 + fr) * 32 + quad * 8;
      bf[i][0] = *(const short8*)&Bh[rbx];
      bf[i][1] = *(const short8*)&Bl[rbx];
    }
    #pragma unroll
    for (int mi = 0; mi < 4; ++mi)
      #pragma unroll
      for (int ni = 0; ni < 4; ++ni) {
        acc[mi][ni] = __builtin_amdgcn_mfma_f32_16x16x32_bf16(
            af[mi][0], bf[ni][0], acc[mi][ni], 0, 0, 0);
        acc[mi][ni] = __builtin_amdgcn_mfma_f32_16x16x32_bf16(
            af[mi][0], bf[ni][1], acc[mi][ni], 0, 0, 0);
        acc[mi][ni] = __builtin_amdgcn_mfma_f32_16x16x32_bf16(
            af[mi][1], bf[ni][0], acc[mi][ni], 0, 0, 0);
      }
    __syncthreads();
  }

  // epilogue: BN + ReLU, write fp32 q/k. C/D: col=lane&15, row=quad*4+reg
  bool isq = rb < 4;
  const float* G  = isq ? g1 : g2;
  const float* Bp = isq ? b1 : b2;
  const float* Mn = isq ? m1 : m2;
  const float* Vv = isq ? v1 : v2;
  float* dst = (isq ? q : k) + (size_t)b * N8_ * C_;
  int mrow0 = (isq ? rb : rb - 4) * 128 + wr + quad * 4;
  int cgl = cb * 128 + wc + fr;
  #pragma unroll
  for (int mi = 0; mi < 4; ++mi) {
    #pragma unroll
    for (int r = 0; r < 4; ++r) {
      int m = mrow0 + mi * 16 + r;
      float sc = G[m] * rsqrtf(Vv[m] + EPS_);
      float bi = Bp[m] - Mn[m] * sc;
      #pragma unroll
      for (int ni = 0; ni < 4; ++ni) {
        float v = fmaxf(fmaf(acc[mi][ni][r], sc, bi), 0.f);
        dst[(size_t)m * C_ + cgl + ni * 16] = v;
      }
    }
  }
}

// -------- kernel 3: sim -> stable softmax(-sim) -> fold alpha*s -> aff2 ---
__global__ __launch_bounds__(256) void k_simsoft(const float* __restrict__ q,
    const float* __restrict__ k, const float* __restrict__ s,
    const float* __restrict__ alpha, float* __restrict__ aff2) {
  int b = blockIdx.y, ct = blockIdx.x;
  int t = threadIdx.x;
  __shared__ float kT[N8_][16];
  const float* kb = k + (size_t)b * N8_ * C_;
  int c0 = ct * 16;
  for (int chunk = 0; chunk < N8_ / 16; ++chunk) {
    int row = chunk * 16 + (t >> 4);
    kT[row][t & 15] = kb[(size_t)row * C_ + c0 + (t & 15)];
  }
  __syncthreads();
  float acc[16];
  #pragma unroll
  for (int i = 0; i < 16; ++i) acc[i] = 0.f;
  const float* qb = q + (size_t)b * N8_ * C_;
  for (int kk = 0; kk < N8_; ++kk) {
    float qv = qb[(size_t)kk * C_ + t];
    float4 k0 = *(const float4*)&kT[kk][0];
    float4 k1 = *(const float4*)&kT[kk][4];
    float4 k2 = *(const float4*)&kT[kk][8];
    float4 k3 = *(const float4*)&kT[kk][12];
    acc[0]  = fmaf(k0.x, qv, acc[0]);  acc[1]  = fmaf(k0.y, qv, acc[1]);
    acc[2]  = fmaf(k0.z, qv, acc[2]);  acc[3]  = fmaf(k0.w, qv, acc[3]);
    acc[4]  = fmaf(k1.x, qv, acc[4]);  acc[5]  = fmaf(k1.y, qv, acc[5]);
    acc[6]  = fmaf(k1.z, qv, acc[6]);  acc[7]  = fmaf(k1.w, qv, acc[7]);
    acc[8]  = fmaf(k2.x, qv, acc[8]);  acc[9]  = fmaf(k2.y, qv, acc[9]);
    acc[10] = fmaf(k2.z, qv, acc[10]); acc[11] = fmaf(k2.w, qv, acc[11]);
    acc[12] = fmaf(k3.x, qv, acc[12]); acc[13] = fmaf(k3.y, qv, acc[13]);
    acc[14] = fmaf(k3.z, qv, acc[14]); acc[15] = fmaf(k3.w, qv, acc[15]);
  }
  int lane = t & 63, wid = t >> 6;
  __shared__ float wmin[16][4];
  __shared__ float wsum[16][4];
  #pragma unroll
  for (int i = 0; i < 16; ++i) {
    float v = acc[i];
    for (int off = 32; off > 0; off >>= 1) v = fminf(v, __shfl_xor(v, off, 64));
    if (lane == 0) wmin[i][wid] = v;
  }
  __syncthreads();
  float w[16];
  #pragma unroll
  for (int i = 0; i < 16; ++i) {
    float m = fminf(fminf(wmin[i][0], wmin[i][1]), fminf(wmin[i][2], wmin[i][3]));
    w[i] = __expf(m - acc[i]);
  }
  #pragma unroll
  for (int i = 0; i < 16; ++i) {
    float v = w[i];
    for (int off = 32; off > 0; off >>= 1) v += __shfl_xor(v, off, 64);
    if (lane == 0) wsum[i][wid] = v;
  }
  __syncthreads();
  float fac = alpha[0] * s[b * C_ + t];
  float* ab = aff2 + (size_t)b * C_ * C_;
  #pragma unroll
  for (int i = 0; i < 16; ++i) {
    float Z = wsum[i][0] + wsum[i][1] + wsum[i][2] + wsum[i][3];
    ab[(size_t)(c0 + i) * C_ + t] = fac * w[i] / Z;
  }
}

// ---------------- kernel 4: out = aff2 @ x + x  (per batch) ---------------
__global__ __launch_bounds__(256) void k_out(const float* __restrict__ aff2,
    const float* __restrict__ x, float* __restrict__ out) {
  int b   = blockIdx.z;
  int cbl = blockIdx.y;
  int nb  = blockIdx.x;
  int t = threadIdx.x;
  __shared__ float As[16][64];
  __shared__ float Bs[16][64];
  const float* ab = aff2 + (size_t)b * C_ * C_ + (size_t)cbl * 64 * C_;
  const float* xb = x + (size_t)b * C_ * N_;
  int n0 = nb * 64;
  int arow = t >> 2, akq = (t & 3) * 4;
  int brow = t >> 4, bnq = (t & 15) * 4;
  int tx = t & 15, ty = t >> 4;
  float acc[4][4] = {{0.f, 0.f, 0.f, 0.f}, {0.f, 0.f, 0.f, 0.f},
                     {0.f, 0.f, 0.f, 0.f}, {0.f, 0.f, 0.f, 0.f}};
  for (int kk = 0; kk < C_; kk += 16) {
    float4 av = *(const float4*)(ab + (size_t)arow * C_ + kk + akq);
    As[akq + 0][arow] = av.x; As[akq + 1][arow] = av.y;
    As[akq + 2][arow] = av.z; As[akq + 3][arow] = av.w;
    float4 bv = *(const float4*)(xb + (size_t)(kk + brow) * N_ + n0 + bnq);
    *(float4*)&Bs[brow][bnq] = bv;
    __syncthreads();
    #pragma unroll
    for (int kt = 0; kt < 16; ++kt) {
      float4 a  = *(const float4*)&As[kt][ty * 4];
      float4 bb = *(const float4*)&Bs[kt][tx * 4];
      acc[0][0] = fmaf(a.x, bb.x, acc[0][0]);
      acc[0][1] = fmaf(a.x, bb.y, acc[0][1]);
      acc[0][2] = fmaf(a.x, bb.z, acc[0][2]);
      acc[0][3] = fmaf(a.x, bb.w, acc[0][3]);
      acc[1][0] = fmaf(a.y, bb.x, acc[1][0]);
      acc[1][1] = fmaf(a.y, bb.y, acc[1][1]);
      acc[1][2] = fmaf(a.y, bb.z, acc[1][2]);
      acc[1][3] = fmaf(a.y, bb.w, acc[1][3]);
      acc[2][0] = fmaf(a.z, bb.x, acc[2][0]);
      acc[2][1] = fmaf(a.z, bb.y, acc[2][1]);
      acc[2][2] = fmaf(a.z, bb.z, acc[2][2]);
      acc[2][3] = fmaf(a.z, bb.w, acc[2][3]);
      acc[3][0] = fmaf(a.w, bb.x, acc[3][0]);
      acc[3][1] = fmaf(a.w, bb.y, acc[3][1]);
      acc[3][2] = fmaf(a.w, bb.z, acc[3][2]);
      acc[3][3] = fmaf(a.w, bb.w, acc[3][3]);
    }
    __syncthreads();
  }
  #pragma unroll
  for (int i = 0; i < 4; ++i) {
    int c = cbl * 64 + ty * 4 + i;
    float4 xr = *(const float4*)(xb + (size_t)c * N_ + n0 + tx * 4);
    float4 o;
    o.x = acc[i][0] + xr.x;
    o.y = acc[i][1] + xr.y;
    o.z = acc[i][2] + xr.z;
    o.w = acc[i][3] + xr.w;
    *(float4*)(out + ((size_t)b * C_ + c) * N_ + n0 + tx * 4) = o;
  }
}

extern "C" void kernel_launch(void* const* d_in, const int* in_sizes, int n_in,
                              void* d_out, int out_size, void* d_ws, size_t ws_size,
                              hipStream_t stream) {
  const float* x     = (const float*)d_in[0];
  const float* Wq    = (const float*)d_in[1];
  const float* g1    = (const float*)d_in[2];
  const float* b1    = (const float*)d_in[3];
  const float* m1    = (const float*)d_in[4];
  const float* v1    = (const float*)d_in[5];
  const float* Wk    = (const float*)d_in[6];
  const float* g2    = (const float*)d_in[7];
  const float* b2    = (const float*)d_in[8];
  const float* m2    = (const float*)d_in[9];
  const float* v2    = (const float*)d_in[10];
  const float* W1    = (const float*)d_in[11];
  const float* W2    = (const float*)d_in[12];
  const float* alpha = (const float*)d_in[13];
  float* out = (float*)d_out;

  float* ws     = (float*)d_ws;
  float* q      = ws;                                 // 4,194,304 f
  float* kbuf   = q + (size_t)B_ * N8_ * C_;          // 4,194,304 f
  float* aff2   = kbuf + (size_t)B_ * N8_ * C_;       // 2,097,152 f
  float* pooled = aff2 + (size_t)B_ * C_ * C_;        // 8,192 f
  float* s      = pooled + B_ * C_;                   // 8,192 f
  ushort* xh    = (ushort*)(s + B_ * C_);             // 33,554,432 u16
  ushort* xl    = xh + (size_t)B_ * C_ * N_;
  ushort* wh    = xl + (size_t)B_ * C_ * N_;          // 4,194,304 u16
  ushort* wl    = wh + (size_t)2 * N8_ * N_;

  // split-bf16 conversions
  k_cvt<<<dim3(4096), 256, 0, stream>>>(x, xh, xl, B_ * C_ * N_ / 4);
  k_cvt<<<dim3(1024), 256, 0, stream>>>(Wq, wh, wl, N8_ * N_ / 4);
  k_cvt<<<dim3(1024), 256, 0, stream>>>(Wk, wh + (size_t)N8_ * N_,
                                        wl + (size_t)N8_ * N_, N8_ * N_ / 4);

  k_pool<<<dim3(16, B_), 256, 0, stream>>>(x, pooled);
  k_semlp<<<dim3(B_), 256, 0, stream>>>(pooled, W1, W2, s);
  k_qk_mfma<<<dim3(2, 8, B_), 256, 0, stream>>>(wh, wl, xh, xl,
                                                g1, b1, m1, v1,
                                                g2, b2, m2, v2, q, kbuf);
  k_simsoft<<<dim3(16, B_), 256, 0, stream>>>(q, kbuf, s, alpha, aff2);
  k_out<<<dim3(64, 4, B_), 256, 0, stream>>>(aff2, x, out);
}

// Round 3
// 688.414 us; speedup vs baseline: 2.1093x; 1.1861x over previous
//
#include <hip/hip_runtime.h>
#include <math.h>

#define B_   32
#define C_   256
#define N_   4096
#define N8_  512
#define C8_  32
#define EPS_ 1e-5f

typedef __attribute__((ext_vector_type(8))) short short8;
typedef __attribute__((ext_vector_type(4))) float f32x4;

__device__ __forceinline__ ushort f2bf(float v) {
  unsigned u = __float_as_uint(v);
  unsigned r = (u + 0x7fffu + ((u >> 16) & 1u)) >> 16;  // RNE to bf16
  return (ushort)r;
}
__device__ __forceinline__ float bf2f(ushort h) {
  return __uint_as_float(((unsigned)h) << 16);
}

// ------------- fp32 -> (bf16 hi, bf16 lo) split conversion (W) ------------
__global__ __launch_bounds__(256) void k_cvt(const float* __restrict__ src,
                                             ushort* __restrict__ hi,
                                             ushort* __restrict__ lo, int n4) {
  int i = blockIdx.x * 256 + threadIdx.x;
  int stride = gridDim.x * 256;
  for (; i < n4; i += stride) {
    float4 v = ((const float4*)src)[i];
    ushort4 h, l;
    h.x = f2bf(v.x); l.x = f2bf(v.x - bf2f(h.x));
    h.y = f2bf(v.y); l.y = f2bf(v.y - bf2f(h.y));
    h.z = f2bf(v.z); l.z = f2bf(v.z - bf2f(h.z));
    h.w = f2bf(v.w); l.w = f2bf(v.w - bf2f(h.w));
    ((ushort4*)hi)[i] = h;
    ((ushort4*)lo)[i] = l;
  }
}

// --- x converter: xh/xl flat [b][c][n], xTh transposed [b][n][c] (hi only),
// --- plus per-(b,c) max-pool partials over each 64-n block. One x read.
__global__ __launch_bounds__(256) void k_cvt_x(const float* __restrict__ x,
    ushort* __restrict__ xh, ushort* __restrict__ xl,
    ushort* __restrict__ xTh, float* __restrict__ partial) {
  int b = blockIdx.z, cb = blockIdx.y, nb = blockIdx.x;  // cb:0..3, nb:0..63
  int t = threadIdx.x;
  int cl  = t >> 2;          // 0..63
  int nl0 = (t & 3) * 16;    // 0,16,32,48
  const float* xp = x + ((size_t)b * C_ + cb * 64 + cl) * N_ + nb * 64 + nl0;
  float v[16];
  *(float4*)&v[0]  = *(const float4*)(xp + 0);
  *(float4*)&v[4]  = *(const float4*)(xp + 4);
  *(float4*)&v[8]  = *(const float4*)(xp + 8);
  *(float4*)&v[12] = *(const float4*)(xp + 12);
  ushort h[16], l[16];
  float mx = -3.402823466e+38f;
  #pragma unroll
  for (int j = 0; j < 16; ++j) {
    h[j] = f2bf(v[j]);
    l[j] = f2bf(v[j] - bf2f(h[j]));
    mx = fmaxf(mx, v[j]);
  }
  size_t fbase = ((size_t)b * C_ + cb * 64 + cl) * N_ + nb * 64 + nl0;
  *(short8*)(xh + fbase)     = *(short8*)&h[0];
  *(short8*)(xh + fbase + 8) = *(short8*)&h[8];
  *(short8*)(xl + fbase)     = *(short8*)&l[0];
  *(short8*)(xl + fbase + 8) = *(short8*)&l[8];
  // pool partial: reduce 4 threads sharing c
  mx = fmaxf(mx, __shfl_xor(mx, 1, 64));
  mx = fmaxf(mx, __shfl_xor(mx, 2, 64));
  if ((t & 3) == 0)
    partial[((size_t)b * C_ + cb * 64 + cl) * 64 + nb] = mx;
  // LDS transpose of hi
  __shared__ ushort lds[64 * 66];
  #pragma unroll
  for (int j = 0; j < 16; ++j) lds[cl * 66 + nl0 + j] = h[j];
  __syncthreads();
  int nr = t >> 2;           // 0..63
  int c0 = (t & 3) * 16;
  ushort o[16];
  #pragma unroll
  for (int j = 0; j < 16; ++j) o[j] = lds[(c0 + j) * 66 + nr];
  size_t tbase = ((size_t)b * N_ + nb * 64 + nr) * C_ + cb * 64 + c0;
  *(short8*)(xTh + tbase)     = *(short8*)&o[0];
  *(short8*)(xTh + tbase + 8) = *(short8*)&o[8];
}

// -------- kernel 1b: s = sigmoid(relu(pool@W1^T)@W2^T), pool from partials -
__global__ __launch_bounds__(256) void k_semlp(const float* __restrict__ partial,
                                               const float* __restrict__ W1,
                                               const float* __restrict__ W2,
                                               float* __restrict__ s) {
  int b = blockIdx.x, t = threadIdx.x;
  __shared__ float p[C_];
  __shared__ float h[C8_];
  float m = -3.402823466e+38f;
  const float* pp = partial + ((size_t)b * C_ + t) * 64;
  #pragma unroll
  for (int j = 0; j < 64; ++j) m = fmaxf(m, pp[j]);
  p[t] = m;
  __syncthreads();
  if (t < C8_) {
    float a = 0.f;
    for (int c = 0; c < C_; ++c) a = fmaf(p[c], W1[t * C_ + c], a);
    h[t] = fmaxf(a, 0.f);
  }
  __syncthreads();
  float a = 0.f;
  #pragma unroll
  for (int j = 0; j < C8_; ++j) a = fmaf(h[j], W2[t * C8_ + j], a);
  s[b * C_ + t] = 1.f / (1.f + __expf(-a));
}

// ------- kernel 2 (MFMA): q/k = relu(bn(W @ x^T)), split-bf16 hi/lo -------
__global__ __launch_bounds__(256) void k_qk_mfma(
    const ushort* __restrict__ Wh, const ushort* __restrict__ Wl,
    const ushort* __restrict__ Xh, const ushort* __restrict__ Xl,
    const float* __restrict__ g1, const float* __restrict__ b1,
    const float* __restrict__ m1, const float* __restrict__ v1,
    const float* __restrict__ g2, const float* __restrict__ b2,
    const float* __restrict__ m2, const float* __restrict__ v2,
    float* __restrict__ q, float* __restrict__ k) {
  int b  = blockIdx.z;
  int rb = blockIdx.y;
  int cb = blockIdx.x;
  __shared__ ushort Ah[128 * 32];
  __shared__ ushort Al[128 * 32];
  __shared__ ushort Bh[128 * 32];
  __shared__ ushort Bl[128 * 32];
  int t = threadIdx.x, wave = t >> 6, lane = t & 63;
  int wr = (wave >> 1) * 64, wc = (wave & 1) * 64;
  int srow = wave * 16 + (lane >> 2);
  int skof = (lane & 3) * 8;
  size_t aoff = (size_t)(rb * 128 + srow) * N_ + skof;
  size_t boff = ((size_t)b * C_ + cb * 128 + srow) * N_ + skof;
  int lb0 = (wave * 16) * 32;

  f32x4 acc[4][4];
  #pragma unroll
  for (int mi = 0; mi < 4; ++mi)
    #pragma unroll
    for (int ni = 0; ni < 4; ++ni)
      acc[mi][ni] = (f32x4){0.f, 0.f, 0.f, 0.f};

  int fr = lane & 15, quad = lane >> 4;
  for (int k0 = 0; k0 < N_; k0 += 32) {
    #pragma unroll
    for (int seg = 0; seg < 2; ++seg) {
      size_t ga = aoff + (size_t)seg * 64 * N_ + k0;
      size_t gb = boff + (size_t)seg * 64 * N_ + k0;
      int lb = lb0 + seg * 64 * 32;
      __builtin_amdgcn_global_load_lds(
          (const __attribute__((address_space(1))) void*)(Wh + ga),
          (__attribute__((address_space(3))) void*)(&Ah[lb]), 16, 0, 0);
      __builtin_amdgcn_global_load_lds(
          (const __attribute__((address_space(1))) void*)(Wl + ga),
          (__attribute__((address_space(3))) void*)(&Al[lb]), 16, 0, 0);
      __builtin_amdgcn_global_load_lds(
          (const __attribute__((address_space(1))) void*)(Xh + gb),
          (__attribute__((address_space(3))) void*)(&Bh[lb]), 16, 0, 0);
      __builtin_amdgcn_global_load_lds(
          (const __attribute__((address_space(1))) void*)(Xl + gb),
          (__attribute__((address_space(3))) void*)(&Bl[lb]), 16, 0, 0);
    }
    __syncthreads();
    short8 af[4][2], bf[4][2];
    #pragma unroll
    for (int i = 0; i < 4; ++i) {
      int ra = (wr + i * 16 + fr) * 32 + quad * 8;
      af[i][0] = *(const short8*)&Ah[ra];
      af[i][1] = *(const short8*)&Al[ra];
      int rbx = (wc + i * 16 + fr) * 32 + quad * 8;
      bf[i][0] = *(const short8*)&Bh[rbx];
      bf[i][1] = *(const short8*)&Bl[rbx];
    }
    #pragma unroll
    for (int mi = 0; mi < 4; ++mi)
      #pragma unroll
      for (int ni = 0; ni < 4; ++ni) {
        acc[mi][ni] = __builtin_amdgcn_mfma_f32_16x16x32_bf16(
            af[mi][0], bf[ni][0], acc[mi][ni], 0, 0, 0);
        acc[mi][ni] = __builtin_amdgcn_mfma_f32_16x16x32_bf16(
            af[mi][0], bf[ni][1], acc[mi][ni], 0, 0, 0);
        acc[mi][ni] = __builtin_amdgcn_mfma_f32_16x16x32_bf16(
            af[mi][1], bf[ni][0], acc[mi][ni], 0, 0, 0);
      }
    __syncthreads();
  }

  bool isq = rb < 4;
  const float* G  = isq ? g1 : g2;
  const float* Bp = isq ? b1 : b2;
  const float* Mn = isq ? m1 : m2;
  const float* Vv = isq ? v1 : v2;
  float* dst = (isq ? q : k) + (size_t)b * N8_ * C_;
  int mrow0 = (isq ? rb : rb - 4) * 128 + wr + quad * 4;
  int cgl = cb * 128 + wc + fr;
  #pragma unroll
  for (int mi = 0; mi < 4; ++mi) {
    #pragma unroll
    for (int r = 0; r < 4; ++r) {
      int m = mrow0 + mi * 16 + r;
      float sc = G[m] * rsqrtf(Vv[m] + EPS_);
      float bi = Bp[m] - Mn[m] * sc;
      #pragma unroll
      for (int ni = 0; ni < 4; ++ni) {
        float v = fmaxf(fmaf(acc[mi][ni][r], sc, bi), 0.f);
        dst[(size_t)m * C_ + cgl + ni * 16] = v;
      }
    }
  }
}

// -- kernel 3: sim -> stable softmax(-sim) -> fold alpha*s -> aff2 (bf16) --
__global__ __launch_bounds__(256) void k_simsoft(const float* __restrict__ q,
    const float* __restrict__ k, const float* __restrict__ s,
    const float* __restrict__ alpha, ushort* __restrict__ aff2) {
  int b = blockIdx.y, ct = blockIdx.x;
  int t = threadIdx.x;
  __shared__ float kT[N8_][16];
  const float* kb = k + (size_t)b * N8_ * C_;
  int c0 = ct * 16;
  for (int chunk = 0; chunk < N8_ / 16; ++chunk) {
    int row = chunk * 16 + (t >> 4);
    kT[row][t & 15] = kb[(size_t)row * C_ + c0 + (t & 15)];
  }
  __syncthreads();
  float acc[16];
  #pragma unroll
  for (int i = 0; i < 16; ++i) acc[i] = 0.f;
  const float* qb = q + (size_t)b * N8_ * C_;
  for (int kk = 0; kk < N8_; ++kk) {
    float qv = qb[(size_t)kk * C_ + t];
    float4 k0 = *(const float4*)&kT[kk][0];
    float4 k1 = *(const float4*)&kT[kk][4];
    float4 k2 = *(const float4*)&kT[kk][8];
    float4 k3 = *(const float4*)&kT[kk][12];
    acc[0]  = fmaf(k0.x, qv, acc[0]);  acc[1]  = fmaf(k0.y, qv, acc[1]);
    acc[2]  = fmaf(k0.z, qv, acc[2]);  acc[3]  = fmaf(k0.w, qv, acc[3]);
    acc[4]  = fmaf(k1.x, qv, acc[4]);  acc[5]  = fmaf(k1.y, qv, acc[5]);
    acc[6]  = fmaf(k1.z, qv, acc[6]);  acc[7]  = fmaf(k1.w, qv, acc[7]);
    acc[8]  = fmaf(k2.x, qv, acc[8]);  acc[9]  = fmaf(k2.y, qv, acc[9]);
    acc[10] = fmaf(k2.z, qv, acc[10]); acc[11] = fmaf(k2.w, qv, acc[11]);
    acc[12] = fmaf(k3.x, qv, acc[12]); acc[13] = fmaf(k3.y, qv, acc[13]);
    acc[14] = fmaf(k3.z, qv, acc[14]); acc[15] = fmaf(k3.w, qv, acc[15]);
  }
  int lane = t & 63, wid = t >> 6;
  __shared__ float wmin[16][4];
  __shared__ float wsum[16][4];
  #pragma unroll
  for (int i = 0; i < 16; ++i) {
    float v = acc[i];
    for (int off = 32; off > 0; off >>= 1) v = fminf(v, __shfl_xor(v, off, 64));
    if (lane == 0) wmin[i][wid] = v;
  }
  __syncthreads();
  float w[16];
  #pragma unroll
  for (int i = 0; i < 16; ++i) {
    float m = fminf(fminf(wmin[i][0], wmin[i][1]), fminf(wmin[i][2], wmin[i][3]));
    w[i] = __expf(m - acc[i]);
  }
  #pragma unroll
  for (int i = 0; i < 16; ++i) {
    float v = w[i];
    for (int off = 32; off > 0; off >>= 1) v += __shfl_xor(v, off, 64);
    if (lane == 0) wsum[i][wid] = v;
  }
  __syncthreads();
  float fac = alpha[0] * s[b * C_ + t];
  ushort* ab = aff2 + (size_t)b * C_ * C_;
  #pragma unroll
  for (int i = 0; i < 16; ++i) {
    float Z = wsum[i][0] + wsum[i][1] + wsum[i][2] + wsum[i][3];
    ab[(size_t)(c0 + i) * C_ + t] = f2bf(fac * w[i] / Z);
  }
}

// ------- kernel 4 (MFMA): out = aff2 @ x + x, A=aff_bf16, B=xTh -----------
__global__ __launch_bounds__(256) void k_out_mfma(
    const ushort* __restrict__ aff, const ushort* __restrict__ xTh,
    const float* __restrict__ x, float* __restrict__ out) {
  int b  = blockIdx.z;
  int cb = blockIdx.y;  // 0..1 : c block of 128
  int nb = blockIdx.x;  // 0..31: n block of 128
  __shared__ ushort Ah[128 * 32];
  __shared__ ushort Bh[128 * 32];
  int t = threadIdx.x, wave = t >> 6, lane = t & 63;
  int wr = (wave >> 1) * 64, wc = (wave & 1) * 64;
  int srow = wave * 16 + (lane >> 2);
  int skof = (lane & 3) * 8;
  size_t aoff = ((size_t)b * C_ + cb * 128 + srow) * C_ + skof;
  size_t boff = ((size_t)b * N_ + nb * 128 + srow) * C_ + skof;
  int lb0 = (wave * 16) * 32;

  f32x4 acc[4][4];
  #pragma unroll
  for (int mi = 0; mi < 4; ++mi)
    #pragma unroll
    for (int ni = 0; ni < 4; ++ni)
      acc[mi][ni] = (f32x4){0.f, 0.f, 0.f, 0.f};

  int fr = lane & 15, quad = lane >> 4;
  for (int k0 = 0; k0 < C_; k0 += 32) {
    #pragma unroll
    for (int seg = 0; seg < 2; ++seg) {
      size_t ga = aoff + (size_t)seg * 64 * C_ + k0;
      size_t gb = boff + (size_t)seg * 64 * C_ + k0;
      int lb = lb0 + seg * 64 * 32;
      __builtin_amdgcn_global_load_lds(
          (const __attribute__((address_space(1))) void*)(aff + ga),
          (__attribute__((address_space(3))) void*)(&Ah[lb]), 16, 0, 0);
      __builtin_amdgcn_global_load_lds(
          (const __attribute__((address_space(1))) void*)(xTh + gb),
          (__attribute__((address_space(3))) void*)(&Bh[lb]), 16, 0, 0);
    }
    __syncthreads();
    short8 af[4], bf[4];
    #pragma unroll
    for (int i = 0; i < 4; ++i) {
      af[i] = *(const short8*)&Ah[(wr + i * 16 + fr) * 32 + quad * 8];
      bf[i] = *(const short8*)&Bh[(wc + i * 16 + fr) * 32 + quad * 8];
    }
    #pragma unroll
    for (int mi = 0; mi < 4; ++mi)
      #pragma unroll
      for (int ni = 0; ni < 4; ++ni)
        acc[mi][ni] = __builtin_amdgcn_mfma_f32_16x16x32_bf16(
            af[mi], bf[ni], acc[mi][ni], 0, 0, 0);
    __syncthreads();
  }

  const float* xb = x + (size_t)b * C_ * N_;
  float* ob = out + (size_t)b * C_ * N_;
  int c0 = cb * 128 + wr + quad * 4;
  int n0 = nb * 128 + wc + fr;
  #pragma unroll
  for (int mi = 0; mi < 4; ++mi) {
    #pragma unroll
    for (int r = 0; r < 4; ++r) {
      int c = c0 + mi * 16 + r;
      #pragma unroll
      for (int ni = 0; ni < 4; ++ni) {
        int n = n0 + ni * 16;
        ob[(size_t)c * N_ + n] = acc[mi][ni][r] + xb[(size_t)c * N_ + n];
      }
    }
  }
}

extern "C" void kernel_launch(void* const* d_in, const int* in_sizes, int n_in,
                              void* d_out, int out_size, void* d_ws, size_t ws_size,
                              hipStream_t stream) {
  const float* x     = (const float*)d_in[0];
  const float* Wq    = (const float*)d_in[1];
  const float* g1    = (const float*)d_in[2];
  const float* b1    = (const float*)d_in[3];
  const float* m1    = (const float*)d_in[4];
  const float* v1    = (const float*)d_in[5];
  const float* Wk    = (const float*)d_in[6];
  const float* g2    = (const float*)d_in[7];
  const float* b2    = (const float*)d_in[8];
  const float* m2    = (const float*)d_in[9];
  const float* v2    = (const float*)d_in[10];
  const float* W1    = (const float*)d_in[11];
  const float* W2    = (const float*)d_in[12];
  const float* alpha = (const float*)d_in[13];
  float* out = (float*)d_out;

  float* ws      = (float*)d_ws;
  float* q       = ws;                                  // 4,194,304 f
  float* kbuf    = q + (size_t)B_ * N8_ * C_;           // 4,194,304 f
  float* partial = kbuf + (size_t)B_ * N8_ * C_;        //   524,288 f
  float* s       = partial + (size_t)B_ * C_ * 64;      //     8,192 f
  ushort* aff    = (ushort*)(s + B_ * C_);              // 2,097,152 u16
  ushort* xh     = aff + (size_t)B_ * C_ * C_;          // 33,554,432 u16
  ushort* xl     = xh + (size_t)B_ * C_ * N_;
  ushort* xTh    = xl + (size_t)B_ * C_ * N_;           // 33,554,432 u16
  ushort* wh     = xTh + (size_t)B_ * C_ * N_;          // 4,194,304 u16
  ushort* wl     = wh + (size_t)2 * N8_ * N_;

  k_cvt_x<<<dim3(64, 4, B_), 256, 0, stream>>>(x, xh, xl, xTh, partial);
  k_cvt<<<dim3(1024), 256, 0, stream>>>(Wq, wh, wl, N8_ * N_ / 4);
  k_cvt<<<dim3(1024), 256, 0, stream>>>(Wk, wh + (size_t)N8_ * N_,
                                        wl + (size_t)N8_ * N_, N8_ * N_ / 4);
  k_semlp<<<dim3(B_), 256, 0, stream>>>(partial, W1, W2, s);
  k_qk_mfma<<<dim3(2, 8, B_), 256, 0, stream>>>(wh, wl, xh, xl,
                                                g1, b1, m1, v1,
                                                g2, b2, m2, v2, q, kbuf);
  k_simsoft<<<dim3(16, B_), 256, 0, stream>>>(q, kbuf, s, alpha, aff);
  k_out_mfma<<<dim3(32, 2, B_), 256, 0, stream>>>(aff, xTh, x, out);
}